// Round 3
// baseline (409.704 us; speedup 1.0000x reference)
//
#include <hip/hip_runtime.h>
#include <hip/hip_bf16.h>

typedef unsigned short ushort_t;
typedef unsigned int uint_t;

#define DIM   256
#define LSEQ  32768
#define HEADS 8
#define CPG   8
#define EPS   1e-5f

typedef float f32x4 __attribute__((ext_vector_type(4)));
typedef short sfrag8 __attribute__((ext_vector_type(8)));

static __device__ __forceinline__ float b2f(ushort_t u) {
    return __uint_as_float((uint_t)u << 16);
}
static __device__ __forceinline__ ushort_t f2bs(float f) {
    union { __hip_bfloat16 h; ushort_t u; } cv;
    cv.h = __float2bfloat16(f);
    return cv.u;
}

// ============ fused transpose + group stats ============
// x fp32 [c][l] -> XT bf16 [l][c]; per-group sum/sumsq atomics
__global__ __launch_bounds__(256) void k_trs(const float* __restrict__ x,
                                             ushort_t* __restrict__ XT,
                                             float* __restrict__ gsum,
                                             float* __restrict__ gsumsq) {
    __shared__ ushort_t tile[64 * 258];
    const int tid = threadIdx.x;
    const int ln  = tid & 63;
    const int wv  = tid >> 6;
    const int l0  = blockIdx.x * 64;
    float gs[8], gs2[8];
    #pragma unroll
    for (int i = 0; i < 8; i++) { gs[i] = 0.f; gs2[i] = 0.f; }
    for (int p = 0; p < 64; p++) {
        int c = wv * 64 + p;
        float v = x[(size_t)c * LSEQ + l0 + ln];
        tile[ln * 258 + c] = f2bs(v);
        gs[p >> 3] += v;
        gs2[p >> 3] += v * v;
    }
    // wave-reduce the 8 group partials (groups wv*8 .. wv*8+7)
    #pragma unroll
    for (int i = 0; i < 8; i++) {
        float a = gs[i], b = gs2[i];
        for (int off = 32; off > 0; off >>= 1) {
            a += __shfl_down(a, off);
            b += __shfl_down(b, off);
        }
        if (ln == 0) {
            atomicAdd(&gsum[wv * 8 + i], a);
            atomicAdd(&gsumsq[wv * 8 + i], b);
        }
    }
    __syncthreads();
    const int lrow = tid >> 2;
    const int cseg = (tid & 3) * 64;
    const uint_t* tp = (const uint_t*)&tile[lrow * 258 + cseg];
    uint_t* dst = (uint_t*)(XT + (size_t)(l0 + lrow) * 256 + cseg);
    #pragma unroll
    for (int g = 0; g < 8; g++) {
        uint4 v4;
        v4.x = tp[g*4+0]; v4.y = tp[g*4+1]; v4.z = tp[g*4+2]; v4.w = tp[g*4+3];
        *(uint4*)(dst + g*4) = v4;
    }
}

// ============ a[c], bb[c] ============
__global__ void k_ab(const float* __restrict__ gn_w, const float* __restrict__ gn_b,
                     const float* __restrict__ gsum, const float* __restrict__ gsumsq,
                     float* __restrict__ A, float* __restrict__ BB) {
    int c = threadIdx.x;
    int g = c >> 3;
    const float inv_n = 1.f / (float)(CPG * LSEQ);
    float mu  = gsum[g] * inv_n;
    float var = gsumsq[g] * inv_n - mu * mu;
    float inv = rsqrtf(var + EPS);
    float a = gn_w[c] * inv;
    A[c]  = a;
    BB[c] = gn_b[c] - mu * a;
}

// ============ folded qkv biases ============
__global__ void k_fold_b(const float* __restrict__ w_qkv, const float* __restrict__ b_qkv,
                         const float* __restrict__ BB, float* __restrict__ BE) {
    int r = blockIdx.x * 256 + threadIdx.x;   // 1536
    float s = b_qkv[r];
    const float4* wr = (const float4*)(w_qkv + (size_t)r * DIM);
    const float4* bb = (const float4*)BB;
    #pragma unroll 4
    for (int c4 = 0; c4 < 64; c4++) {
        float4 w = wr[c4], b = bb[c4];
        s += w.x*b.x + w.y*b.y + w.z*b.z + w.w*b.w;
    }
    BE[r] = s;
}

// ============ folded k/v weights: WEB bf16 [r'][c], r' = h*128 + part*64 + j ============
__global__ void k_fold_w(const float* __restrict__ w_qkv, const float* __restrict__ A,
                         const float* __restrict__ BE,
                         ushort_t* __restrict__ WEB, float* __restrict__ BE2) {
    int idx = blockIdx.x * 256 + threadIdx.x;   // 262144
    int rp = idx >> 8, c = idx & 255;
    int h = rp >> 7, sub = rp & 127, part = sub >> 6, j = sub & 63;
    int orig = 512 + part * 512 + h * 64 + j;
    WEB[(size_t)rp * 256 + c] = f2bs(w_qkv[(size_t)orig * 256 + c] * A[c]);
    if (c == 0) BE2[rp] = BE[orig];
}

// ============ fused kv-GEMM + exp + context GEMM ============
// grid 512: h = bid&7, super-chunk (512 cols) = bid>>3; 8 sub-chunks of 64 cols.
// A (weights) in registers, B (XT) staged in padded LDS. 16x16x32 MFMA (r2-validated layouts).
__global__ __launch_bounds__(256, 2) void k_attn(const ushort_t* __restrict__ XT,
                                                 const ushort_t* __restrict__ WEB,
                                                 const float* __restrict__ BE2,
                                                 float* __restrict__ S, float* __restrict__ Z) {
    __shared__ __align__(16) ushort_t xs[64 * 264];  // 64 cols x 256 ch, stride 264 shorts
    __shared__ __align__(16) ushort_t ek[64 * 72];   // exp(k): 64 rows x 64 cols, stride 72
    __shared__ __align__(16) ushort_t vv[64 * 72];   // v tile
    const int tid  = threadIdx.x;
    const int lane = tid & 63;
    const int wv   = __builtin_amdgcn_readfirstlane(tid >> 6);
    const int ln   = lane & 15;
    const int q    = lane >> 4;
    const int mh   = wv >> 1;    // m-half: 0 -> k rows 0..63, 1 -> v rows 64..127
    const int nh   = wv & 1;     // n-half: 32-col half of the 64-col sub-chunk
    const int h    = blockIdx.x & 7;
    const int cg0  = (blockIdx.x >> 3) * 512;

    // A-fragment preload: 4 m-tiles x 8 k-steps (K=256), 128 VGPRs
    sfrag8 Af[4][8];
    #pragma unroll
    for (int mt = 0; mt < 4; mt++) {
        const ushort_t* ap = WEB + (size_t)(h*128 + mh*64 + mt*16 + ln) * 256 + q*8;
        #pragma unroll
        for (int k0 = 0; k0 < 8; k0++) Af[mt][k0] = *(const sfrag8*)(ap + k0*32);
    }
    // bias per C-layout row
    float bias[4][4];
    #pragma unroll
    for (int mt = 0; mt < 4; mt++)
        #pragma unroll
        for (int r = 0; r < 4; r++)
            bias[mt][r] = BE2[h*128 + mh*64 + mt*16 + q*4 + r];

    f32x4 Sacc[4];
    #pragma unroll
    for (int nt = 0; nt < 4; nt++)
        #pragma unroll
        for (int e = 0; e < 4; e++) Sacc[nt][e] = 0.f;
    float zsum = 0.f;

    for (int sc = 0; sc < 8; sc++) {
        const int l0 = cg0 + sc * 64;
        // stage XT tile: 64 rows x 512 B, coalesced 16 B/lane, padded LDS rows
        #pragma unroll
        for (int it = 0; it < 8; it++) {
            int idx = it * 256 + tid;
            int row = idx >> 5, seg = idx & 31;
            *(uint4*)&xs[row * 264 + seg * 8] =
                *(const uint4*)(XT + (size_t)(l0 + row) * 256 + seg * 8);
        }
        __syncthreads();

        // GEMM1: this wave: 64 rows (4 m-tiles) x 32 cols (2 n-tiles), K=256
        f32x4 acc[4][2];
        #pragma unroll
        for (int mt = 0; mt < 4; mt++)
            #pragma unroll
            for (int nt = 0; nt < 2; nt++)
                #pragma unroll
                for (int e = 0; e < 4; e++) acc[mt][nt][e] = 0.f;

        #pragma unroll
        for (int k0 = 0; k0 < 8; k0++) {
            sfrag8 b0 = *(const sfrag8*)&xs[(nh*32 + ln)      * 264 + k0*32 + q*8];
            sfrag8 b1 = *(const sfrag8*)&xs[(nh*32 + 16 + ln) * 264 + k0*32 + q*8];
            #pragma unroll
            for (int mt = 0; mt < 4; mt++) {
                acc[mt][0] = __builtin_amdgcn_mfma_f32_16x16x32_bf16(Af[mt][k0], b0, acc[mt][0], 0, 0, 0);
                acc[mt][1] = __builtin_amdgcn_mfma_f32_16x16x32_bf16(Af[mt][k0], b1, acc[mt][1], 0, 0, 0);
            }
        }

        // write ek (waves mh=0, with exp) / vv (waves mh=1)
        if (mh == 0) {
            #pragma unroll
            for (int mt = 0; mt < 4; mt++)
                #pragma unroll
                for (int nt = 0; nt < 2; nt++)
                    #pragma unroll
                    for (int r = 0; r < 4; r++) {
                        int row = mt*16 + q*4 + r;
                        int col = nh*32 + nt*16 + ln;
                        ek[row * 72 + col] = f2bs(__expf(acc[mt][nt][r] + bias[mt][r]));
                    }
        } else {
            #pragma unroll
            for (int mt = 0; mt < 4; mt++)
                #pragma unroll
                for (int nt = 0; nt < 2; nt++)
                    #pragma unroll
                    for (int r = 0; r < 4; r++) {
                        int row = mt*16 + q*4 + r;
                        int col = nh*32 + nt*16 + ln;
                        vv[row * 72 + col] = f2bs(acc[mt][nt][r] + bias[mt][r]);
                    }
        }
        __syncthreads();

        // GEMM2: S[kc][e] += ek @ vv^T over this sub-chunk (K=64)
        #pragma unroll
        for (int k0 = 0; k0 < 2; k0++) {
            sfrag8 a = *(const sfrag8*)&ek[(wv*16 + ln) * 72 + k0*32 + q*8];
            #pragma unroll
            for (int nt = 0; nt < 4; nt++) {
                sfrag8 b = *(const sfrag8*)&vv[(nt*16 + ln) * 72 + k0*32 + q*8];
                Sacc[nt] = __builtin_amdgcn_mfma_f32_16x16x32_bf16(a, b, Sacc[nt], 0, 0, 0);
            }
        }
        // Z partials (wave 2; its next-iteration barrier protects ek from overwrite)
        if (wv == 2) {
            float zs = 0.f;
            #pragma unroll 8
            for (int j = 0; j < 64; j++) zs += b2f(ek[lane * 72 + j]);
            zsum += zs;
        }
    }

    float* Sh = S + h * 4096;
    #pragma unroll
    for (int nt = 0; nt < 4; nt++)
        #pragma unroll
        for (int r = 0; r < 4; r++)
            atomicAdd(&Sh[(wv*16 + q*4 + r) * 64 + nt*16 + ln], Sacc[nt][r]);
    if (wv == 2) atomicAdd(&Z[h * 64 + lane], zsum);
}

// ============ W2[d][hc] = sum_e w_out[d][h64+e] * S[hc][e] / Z[hc] ============
__global__ void k_w2(const float* __restrict__ w_out, const float* __restrict__ S,
                     const float* __restrict__ Z, float* __restrict__ W2) {
    int d  = blockIdx.x >> 1;
    int hc = ((blockIdx.x & 1) << 8) + threadIdx.x;
    int h64 = hc & ~63;
    float invZ = 1.f / Z[hc];
    const float4* wo = (const float4*)(w_out + (size_t)d * 512 + h64);
    const float4* Sr = (const float4*)(S + (size_t)hc * 64);
    float s = 0.f;
    #pragma unroll
    for (int e4 = 0; e4 < 16; e4++) {
        float4 a = wo[e4], b = Sr[e4];
        s += a.x*b.x + a.y*b.y + a.z*b.z + a.w*b.w;
    }
    W2[(size_t)d * 512 + hc] = s * invZ;
}

// ============ W3B[d][c] bf16 + B3[d] ============
__global__ void k_w3(const float* __restrict__ w_qkv, const float* __restrict__ W2,
                     const float* __restrict__ A, const float* __restrict__ BE,
                     const float* __restrict__ b_out,
                     ushort_t* __restrict__ W3B, float* __restrict__ B3) {
    int d = blockIdx.x, c = threadIdx.x;
    const float* W2d = W2 + (size_t)d * 512;
    float s = 0.f;
    #pragma unroll 4
    for (int hc = 0; hc < 512; hc++)
        s += W2d[hc] * w_qkv[(size_t)hc * 256 + c];
    W3B[(size_t)d * 256 + c] = f2bs(s * A[c]);
    __shared__ float red[256];
    red[c] = W2d[c] * BE[c] + W2d[256 + c] * BE[256 + c];
    __syncthreads();
    for (int off = 128; off > 0; off >>= 1) {
        if (c < off) red[c] += red[c + off];
        __syncthreads();
    }
    if (c == 0) B3[d] = b_out[d] + red[0];
}

// ============ final GEMM: out = W3B @ xT + b3 ============
// grid 1024: m-half = bid&1 (128 rows), 64-col chunk = bid>>1
__global__ __launch_bounds__(256, 2) void k_final(const ushort_t* __restrict__ XT,
                                                  const ushort_t* __restrict__ W3B,
                                                  const float* __restrict__ B3,
                                                  float* __restrict__ out) {
    __shared__ __align__(16) ushort_t xs[64 * 264];
    const int tid  = threadIdx.x;
    const int lane = tid & 63;
    const int wv   = __builtin_amdgcn_readfirstlane(tid >> 6);
    const int ln   = lane & 15;
    const int q    = lane >> 4;
    const int mh   = wv >> 1;
    const int nh   = wv & 1;
    const int m0   = (blockIdx.x & 1) * 128;
    const int l0   = (blockIdx.x >> 1) * 64;

    sfrag8 Af[4][8];
    #pragma unroll
    for (int mt = 0; mt < 4; mt++) {
        const ushort_t* ap = W3B + (size_t)(m0 + mh*64 + mt*16 + ln) * 256 + q*8;
        #pragma unroll
        for (int k0 = 0; k0 < 8; k0++) Af[mt][k0] = *(const sfrag8*)(ap + k0*32);
    }
    float bias[4][4];
    #pragma unroll
    for (int mt = 0; mt < 4; mt++)
        #pragma unroll
        for (int r = 0; r < 4; r++)
            bias[mt][r] = B3[m0 + mh*64 + mt*16 + q*4 + r];

    #pragma unroll
    for (int it = 0; it < 8; it++) {
        int idx = it * 256 + tid;
        int row = idx >> 5, seg = idx & 31;
        *(uint4*)&xs[row * 264 + seg * 8] =
            *(const uint4*)(XT + (size_t)(l0 + row) * 256 + seg * 8);
    }
    __syncthreads();

    f32x4 acc[4][2];
    #pragma unroll
    for (int mt = 0; mt < 4; mt++)
        #pragma unroll
        for (int nt = 0; nt < 2; nt++)
            #pragma unroll
            for (int e = 0; e < 4; e++) acc[mt][nt][e] = 0.f;

    #pragma unroll
    for (int k0 = 0; k0 < 8; k0++) {
        sfrag8 b0 = *(const sfrag8*)&xs[(nh*32 + ln)      * 264 + k0*32 + q*8];
        sfrag8 b1 = *(const sfrag8*)&xs[(nh*32 + 16 + ln) * 264 + k0*32 + q*8];
        #pragma unroll
        for (int mt = 0; mt < 4; mt++) {
            acc[mt][0] = __builtin_amdgcn_mfma_f32_16x16x32_bf16(Af[mt][k0], b0, acc[mt][0], 0, 0, 0);
            acc[mt][1] = __builtin_amdgcn_mfma_f32_16x16x32_bf16(Af[mt][k0], b1, acc[mt][1], 0, 0, 0);
        }
    }

    #pragma unroll
    for (int mt = 0; mt < 4; mt++)
        #pragma unroll
        for (int nt = 0; nt < 2; nt++)
            #pragma unroll
            for (int r = 0; r < 4; r++) {
                int row = m0 + mh*64 + mt*16 + q*4 + r;
                int col = l0 + nh*32 + nt*16 + ln;
                out[(size_t)row * LSEQ + col] = acc[mt][nt][r] + bias[mt][r];
            }
}

// ============ launch ============
extern "C" void kernel_launch(void* const* d_in, const int* in_sizes, int n_in,
                              void* d_out, int out_size, void* d_ws, size_t ws_size,
                              hipStream_t stream) {
    const float* x     = (const float*)d_in[0];
    const float* gn_w  = (const float*)d_in[1];
    const float* gn_b  = (const float*)d_in[2];
    const float* w_qkv = (const float*)d_in[3];
    const float* b_qkv = (const float*)d_in[4];
    const float* w_out = (const float*)d_in[5];
    const float* b_out = (const float*)d_in[6];
    float* out = (float*)d_out;
    float* ws  = (float*)d_ws;

    float*    gsum   = ws + 0;        // 32
    float*    gsumsq = ws + 32;       // 32
    float*    S      = ws + 64;       // 32768
    float*    Z      = ws + 32832;    // 512   [zeroed through 33344]
    float*    A      = ws + 33344;    // 256
    float*    BB     = ws + 33600;    // 256
    float*    BE     = ws + 33856;    // 1536
    float*    BE2    = ws + 35392;    // 1024
    ushort_t* WEB    = (ushort_t*)(ws + 36416);    // 1024*256 bf16 (65536 f)
    float*    W2     = ws + 101952;   // 131072
    ushort_t* W3B    = (ushort_t*)(ws + 233024);   // 256*256 bf16 (32768 f)
    float*    B3     = ws + 265792;   // 256
    ushort_t* XT     = (ushort_t*)(ws + 266048);   // 32768*256 bf16 (4194304 f)

    hipMemsetAsync(ws, 0, 33344 * sizeof(float), stream);   // gsum, gsumsq, S, Z
    k_trs   <<<512,  256, 0, stream>>>(x, XT, gsum, gsumsq);
    k_ab    <<<1,    256, 0, stream>>>(gn_w, gn_b, gsum, gsumsq, A, BB);
    k_fold_b<<<6,    256, 0, stream>>>(w_qkv, b_qkv, BB, BE);
    k_fold_w<<<1024, 256, 0, stream>>>(w_qkv, A, BE, WEB, BE2);
    k_attn  <<<512,  256, 0, stream>>>(XT, WEB, BE2, S, Z);
    k_w2    <<<512,  256, 0, stream>>>(w_out, S, Z, W2);
    k_w3    <<<256,  256, 0, stream>>>(w_qkv, W2, A, BE, b_out, W3B, B3);
    k_final <<<1024, 256, 0, stream>>>(XT, W3B, B3, out);
}